// Round 4
// baseline (592.930 us; speedup 1.0000x reference)
//
#include <hip/hip_runtime.h>

// SelfAttention: X[8192,1024] -> Q,K,V = X@W^T+b ; P=exp(cosine(Q,K)) ; out = P@V / rowsum(P)
// R4 change vs R3: score GEMM moved to MX-fp8 (e4m3, unit scales) via
// v_mfma_scale_f32_32x32x64_f8f6f4 — halves staging bytes, ds_reads, barriers and
// MFMA cycles of the dominant kernel. Q,K stored fp8 from qkv epilogue (raw, unnormalized;
// cosine norm still applied in fp32 epilogue). P and the PV GEMM stay bf16: absmax budget
// is dominated by P/V quantization (fp8 there would be ~16x the rounding error).
// Frag layout (assumed, natural ext of verified bf16 32x32): A row=lane&31, k=(lane>>5)*32+i.

#define SEQ 8192
#define MID 1024
#define EMB 1024

typedef __attribute__((ext_vector_type(8))) short short8x;
typedef __attribute__((ext_vector_type(16))) float float16x;
typedef __attribute__((ext_vector_type(4))) int int4x;
typedef __attribute__((ext_vector_type(8))) int int8x;

__device__ __forceinline__ unsigned short f2bf(float x) {
  union { float f; unsigned u; } v; v.f = x;
  unsigned r = v.u + 0x7FFFu + ((v.u >> 16) & 1u);  // round-to-nearest-even
  return (unsigned short)(r >> 16);
}
__device__ __forceinline__ float bf2f(unsigned short h) {
  union { unsigned u; float f; } v; v.u = ((unsigned)h) << 16;
  return v.f;
}

__device__ __forceinline__ void g2l16(const void* g, void* lds) {
  __builtin_amdgcn_global_load_lds(
      (const __attribute__((address_space(1))) unsigned int*)g,
      (__attribute__((address_space(3))) unsigned int*)lds, 16, 0, 0);
}

// ---------------- bf16 NT GEMM core (qkv, out) ----------------
// C[128x128] = A[m0..,:K] * B[n0..,:K]^T; 4 waves, wave quadrant 64x64 = 2x2 of 32x32.
__device__ __forceinline__ void gemm128_nt(
    const unsigned short* __restrict__ A, const unsigned short* __restrict__ B,
    long lda, long ldb, int m0, int n0, int K,
    unsigned short* As, unsigned short* Bs, float16x acc[2][2]) {
  const int tid = threadIdx.x;
  const int w = tid >> 6;
  const int l = tid & 63;
  const int wm = (w & 1) << 6;
  const int wn = (w >> 1) << 6;
  const int srow = l >> 3;
  const int skg = (l & 7) ^ srow;
  const int l31 = l & 31;
  const int lh = l >> 5;
  const int swz = l31 & 7;

  for (int k0 = 0; k0 < K; k0 += 64) {
    __syncthreads();
#pragma unroll
    for (int r = 0; r < 4; ++r) {
      const int rr = (w * 4 + r) * 8 + srow;
      g2l16(A + (long)(m0 + rr) * lda + k0 + skg * 8, As + (w * 4 + r) * 512);
      g2l16(B + (long)(n0 + rr) * ldb + k0 + skg * 8, Bs + (w * 4 + r) * 512);
    }
    __syncthreads();
#pragma unroll
    for (int ks = 0; ks < 4; ++ks) {
      const int kg = ks * 2 + lh;
      short8x av[2], bv[2];
#pragma unroll
      for (int t = 0; t < 2; ++t) {
        const int ar = wm + t * 32 + l31;
        av[t] = *(const short8x*)(As + ar * 64 + ((kg ^ swz) << 3));
        const int br = wn + t * 32 + l31;
        bv[t] = *(const short8x*)(Bs + br * 64 + ((kg ^ swz) << 3));
      }
#pragma unroll
      for (int tm = 0; tm < 2; ++tm)
#pragma unroll
        for (int tn = 0; tn < 2; ++tn)
          acc[tm][tn] = __builtin_amdgcn_mfma_f32_32x32x16_bf16(av[tm], bv[tn], acc[tm][tn], 0, 0, 0);
    }
  }
}

// ---------------- fp8 NT GEMM core (score) ----------------
// A,B are fp8 e4m3 row-major, K-contiguous; lda/ldb/Kbytes in BYTES. BK=128 bytes.
// LDS rows 128 B (32 banks exactly); 16-B chunk swizzle c_eff = c ^ (row&7).
__device__ __forceinline__ void gemm128_nt_f8(
    const unsigned char* __restrict__ A, const unsigned char* __restrict__ B,
    long lda, long ldb, int m0, int n0, int Kbytes,
    unsigned char* As, unsigned char* Bs, float16x acc[2][2]) {
  const int tid = threadIdx.x;
  const int w = tid >> 6;
  const int l = tid & 63;
  const int wm = (w & 1) << 6;
  const int wn = (w >> 1) << 6;
  const int srow = l >> 3;
  const int skg = (l & 7) ^ srow;      // 16-B chunk units
  const int l31 = l & 31;
  const int lh = l >> 5;
  const int swz = l31 & 7;

  for (int k0 = 0; k0 < Kbytes; k0 += 128) {
    __syncthreads();
#pragma unroll
    for (int r = 0; r < 4; ++r) {
      const int rr = (w * 4 + r) * 8 + srow;
      g2l16(A + (long)(m0 + rr) * lda + k0 + skg * 16, As + (w * 4 + r) * 1024);
      g2l16(B + (long)(n0 + rr) * ldb + k0 + skg * 16, Bs + (w * 4 + r) * 1024);
    }
    __syncthreads();
#pragma unroll
    for (int ks = 0; ks < 2; ++ks) {
      const int c0 = ks * 4 + lh * 2;  // global 16-B chunk index of this lane's 32 B
      int8x av[2], bv[2];
#pragma unroll
      for (int t = 0; t < 2; ++t) {
        {
          const unsigned char* base = As + (wm + t * 32 + l31) * 128;
          int4x lo = *(const int4x*)(base + ((c0 ^ swz) << 4));
          int4x hi = *(const int4x*)(base + (((c0 + 1) ^ swz) << 4));
          int8x a; a[0]=lo[0]; a[1]=lo[1]; a[2]=lo[2]; a[3]=lo[3];
          a[4]=hi[0]; a[5]=hi[1]; a[6]=hi[2]; a[7]=hi[3];
          av[t] = a;
        }
        {
          const unsigned char* base = Bs + (wn + t * 32 + l31) * 128;
          int4x lo = *(const int4x*)(base + ((c0 ^ swz) << 4));
          int4x hi = *(const int4x*)(base + (((c0 + 1) ^ swz) << 4));
          int8x b; b[0]=lo[0]; b[1]=lo[1]; b[2]=lo[2]; b[3]=lo[3];
          b[4]=hi[0]; b[5]=hi[1]; b[6]=hi[2]; b[7]=hi[3];
          bv[t] = b;
        }
      }
#pragma unroll
      for (int tm = 0; tm < 2; ++tm)
#pragma unroll
        for (int tn = 0; tn < 2; ++tn)
          acc[tm][tn] = __builtin_amdgcn_mfma_scale_f32_32x32x64_f8f6f4(
              av[tm], bv[tn], acc[tm][tn], 0, 0,  // cbsz=fp8, blgp=fp8
              0, 0x7F7F7F7F,                      // opsel_a, scale_a = 1.0 (e8m0 127)
              0, 0x7F7F7F7F);                     // opsel_b, scale_b = 1.0
    }
  }
}

__global__ void cvt_kernel(const float* __restrict__ src, unsigned short* __restrict__ dst, int n) {
  int i = (blockIdx.x * 256 + threadIdx.x) * 4;
  if (i + 3 < n) {
    float4 v = *(const float4*)(src + i);
    ushort4 o;
    o.x = f2bf(v.x); o.y = f2bf(v.y); o.z = f2bf(v.z); o.w = f2bf(v.w);
    *(ushort4*)(dst + i) = o;
  }
}

__global__ void cvtw_kernel(const float* __restrict__ wq, const float* __restrict__ wk,
                            const float* __restrict__ wv, unsigned short* __restrict__ dst) {
  int idx4 = (blockIdx.x * 256 + threadIdx.x) * 4;
  const int per = MID * EMB;
  int t = idx4 / per;
  int off = idx4 - t * per;
  const float* src = (t == 0) ? wq : (t == 1) ? wk : wv;
  float4 v = *(const float4*)(src + off);
  ushort4 o;
  o.x = f2bf(v.x); o.y = f2bf(v.y); o.z = f2bf(v.z); o.w = f2bf(v.w);
  *(ushort4*)(dst + idx4) = o;
}

__global__ __launch_bounds__(256) void qkv_kernel(
    const unsigned short* __restrict__ Xb, const unsigned short* __restrict__ Wb,
    const float* __restrict__ bq, const float* __restrict__ bk, const float* __restrict__ bv,
    unsigned char* __restrict__ Q8, unsigned char* __restrict__ K8,
    unsigned short* __restrict__ VT, float* __restrict__ sumsq) {
  __shared__ unsigned short smem[16384];  // 32 KB: As/Bs during GEMM, transpose tile after
  unsigned short* As = smem;
  unsigned short* Bs = smem + 8192;
  const int z = blockIdx.z;
  const int m0 = blockIdx.y * 128;
  const int n0 = blockIdx.x * 128;
  float16x acc[2][2];
#pragma unroll
  for (int i = 0; i < 2; ++i)
#pragma unroll
    for (int j = 0; j < 2; ++j)
#pragma unroll
      for (int e = 0; e < 16; ++e) acc[i][j][e] = 0.f;

  gemm128_nt(Xb, Wb + (long)z * MID * EMB, EMB, EMB, m0, n0, EMB, As, Bs, acc);

  const int tid = threadIdx.x;
  const int l = tid & 63, w = tid >> 6;
  const int wm = (w & 1) << 6, wn = (w >> 1) << 6;
  const int l31 = l & 31, lh = l >> 5;
  const float* bias = (z == 0) ? bq : (z == 1) ? bk : bv;
  float bvv[2];
#pragma unroll
  for (int tn = 0; tn < 2; ++tn) bvv[tn] = bias[n0 + wn + tn * 32 + l31];
#pragma unroll
  for (int tm = 0; tm < 2; ++tm)
#pragma unroll
    for (int tn = 0; tn < 2; ++tn)
#pragma unroll
      for (int r = 0; r < 16; ++r) acc[tm][tn][r] += bvv[tn];

  __syncthreads();  // all waves done reading As/Bs

  if (z < 2) {
    // bf16 [row][col] tile, chunk ^= row&7 swizzle; pack col-pairs via shfl
#pragma unroll
    for (int tm = 0; tm < 2; ++tm)
#pragma unroll
      for (int tn = 0; tn < 2; ++tn) {
        const int rcol = wn + tn * 32 + l31;
#pragma unroll
        for (int r = 0; r < 16; ++r) {
          float v = acc[tm][tn][r];
          float po = __shfl_xor(v, 1);
          if (!(l & 1)) {
            const int rrow = wm + tm * 32 + (r & 3) + 8 * (r >> 2) + 4 * lh;
            const int chunk = (rcol >> 3) ^ (rrow & 7);
            unsigned pk = (unsigned)f2bf(v) | ((unsigned)f2bf(po) << 16);
            *(unsigned*)(smem + rrow * 128 + (chunk << 3) + (rcol & 7)) = pk;
          }
        }
      }
    __syncthreads();
    unsigned char* O8 = z ? K8 : Q8;
    float* ss = sumsq + (long)z * SEQ;
#pragma unroll
    for (int round = 0; round < 8; ++round) {
      const int row = round * 16 + (tid >> 4);
      const int c = tid & 15;
      short8x vv = *(const short8x*)(smem + row * 128 + ((c ^ (row & 7)) << 3));
      float f[8];
#pragma unroll
      for (int j = 0; j < 8; ++j) f[j] = bf2f((unsigned short)vv[j]);
      int lo = __builtin_amdgcn_cvt_pk_fp8_f32(f[0], f[1], 0, false);
      lo = __builtin_amdgcn_cvt_pk_fp8_f32(f[2], f[3], lo, true);
      int hi = __builtin_amdgcn_cvt_pk_fp8_f32(f[4], f[5], 0, false);
      hi = __builtin_amdgcn_cvt_pk_fp8_f32(f[6], f[7], hi, true);
      int2 pk; pk.x = lo; pk.y = hi;
      *(int2*)(O8 + (long)(m0 + row) * MID + n0 + c * 8) = pk;
      float s = 0.f;
#pragma unroll
      for (int j = 0; j < 8; ++j) s += f[j] * f[j];
      s += __shfl_xor(s, 1); s += __shfl_xor(s, 2);
      s += __shfl_xor(s, 4); s += __shfl_xor(s, 8);
      if (c == 0) atomicAdd(ss + m0 + row, s);
    }
  } else {
    // V transposed (bf16): LDS tile [nn][mm]
#pragma unroll
    for (int tm = 0; tm < 2; ++tm)
#pragma unroll
      for (int tn = 0; tn < 2; ++tn) {
        const int nn = wn + tn * 32 + l31;
#pragma unroll
        for (int g = 0; g < 4; ++g) {
          const int mm = wm + tm * 32 + 8 * g + 4 * lh;
          const int chunk = (mm >> 3) ^ (nn & 7);
          ushort4 pk;
          pk.x = f2bf(acc[tm][tn][g * 4 + 0]);
          pk.y = f2bf(acc[tm][tn][g * 4 + 1]);
          pk.z = f2bf(acc[tm][tn][g * 4 + 2]);
          pk.w = f2bf(acc[tm][tn][g * 4 + 3]);
          *(ushort4*)(smem + nn * 128 + (chunk << 3) + (mm & 7)) = pk;
        }
      }
    __syncthreads();
#pragma unroll
    for (int round = 0; round < 8; ++round) {
      const int nn = round * 16 + (tid >> 4);
      const int c = tid & 15;
      short8x vv = *(const short8x*)(smem + nn * 128 + ((c ^ (nn & 7)) << 3));
      *(short8x*)(VT + (long)(n0 + nn) * SEQ + m0 + c * 8) = vv;
    }
  }
}

__global__ __launch_bounds__(256) void score_kernel(
    const unsigned char* __restrict__ Q8, const unsigned char* __restrict__ K8,
    const float* __restrict__ sumsq,
    unsigned short* __restrict__ P, float* __restrict__ denom) {
  __shared__ unsigned short smem[16384];  // 32 KB: fp8 As/Bs (16K+16K), then bf16 exp tile
  unsigned char* As = (unsigned char*)smem;
  unsigned char* Bs = (unsigned char*)smem + 16384;
  const int m0 = blockIdx.y * 128;
  const int n0 = blockIdx.x * 128;
  float16x acc[2][2];
#pragma unroll
  for (int i = 0; i < 2; ++i)
#pragma unroll
    for (int j = 0; j < 2; ++j)
#pragma unroll
      for (int e = 0; e < 16; ++e) acc[i][j][e] = 0.f;

  gemm128_nt_f8(Q8, K8, MID, MID, m0, n0, MID, As, Bs, acc);

  const int tid = threadIdx.x;
  const int l = tid & 63, w = tid >> 6;
  const int wm = (w & 1) << 6, wn = (w >> 1) << 6;
  const int l31 = l & 31, lh = l >> 5;

  float ik[2];
#pragma unroll
  for (int tn = 0; tn < 2; ++tn)
    ik[tn] = rsqrtf(sumsq[SEQ + n0 + wn + tn * 32 + l31]);

  __syncthreads();  // all waves done reading As/Bs

#pragma unroll
  for (int tm = 0; tm < 2; ++tm)
#pragma unroll
    for (int r = 0; r < 16; ++r) {
      const int rrow = wm + tm * 32 + (r & 3) + 8 * (r >> 2) + 4 * lh;
      const float qi = rsqrtf(sumsq[m0 + rrow]);
#pragma unroll
      for (int tn = 0; tn < 2; ++tn) {
        float v = __expf(acc[tm][tn][r] * qi * ik[tn]);
        float po = __shfl_xor(v, 1);
        if (!(l & 1)) {
          const int rcol = wn + tn * 32 + l31;  // even
          const int chunk = (rcol >> 3) ^ (rrow & 7);
          unsigned pk = (unsigned)f2bf(v) | ((unsigned)f2bf(po) << 16);
          *(unsigned*)(smem + rrow * 128 + (chunk << 3) + (rcol & 7)) = pk;
        }
      }
    }
  __syncthreads();
#pragma unroll
  for (int round = 0; round < 8; ++round) {
    const int row = round * 16 + (tid >> 4);
    const int c = tid & 15;
    short8x vv = *(const short8x*)(smem + row * 128 + ((c ^ (row & 7)) << 3));
    *(short8x*)(P + (long)(m0 + row) * SEQ + n0 + c * 8) = vv;
    float s = 0.f;
#pragma unroll
    for (int j = 0; j < 8; ++j) s += bf2f((unsigned short)vv[j]);
    s += __shfl_xor(s, 1); s += __shfl_xor(s, 2);
    s += __shfl_xor(s, 4); s += __shfl_xor(s, 8);
    if (c == 0) atomicAdd(denom + m0 + row, s);
  }
}

__global__ __launch_bounds__(256) void out_kernel(
    const unsigned short* __restrict__ P, const unsigned short* __restrict__ VT,
    const float* __restrict__ denom, float* __restrict__ out) {
  __shared__ unsigned short smem[16384];
  unsigned short* As = smem;
  unsigned short* Bs = smem + 8192;
  // grid: x = m (fast, 64), y = e (8) -> the 8 e-blocks of one P-stripe share an XCD's L2
  const int m0 = blockIdx.x * 128;
  const int n0 = blockIdx.y * 128;
  float16x acc[2][2];
#pragma unroll
  for (int i = 0; i < 2; ++i)
#pragma unroll
    for (int j = 0; j < 2; ++j)
#pragma unroll
      for (int e = 0; e < 16; ++e) acc[i][j][e] = 0.f;

  gemm128_nt(P, VT, SEQ, SEQ, m0, n0, SEQ, As, Bs, acc);

  const int l = threadIdx.x & 63, w = threadIdx.x >> 6;
  const int wm = (w & 1) << 6, wn = (w >> 1) << 6;
  const int l31 = l & 31, lh = l >> 5;
#pragma unroll
  for (int tm = 0; tm < 2; ++tm)
#pragma unroll
    for (int r = 0; r < 16; ++r) {
      const int row = m0 + wm + tm * 32 + (r & 3) + 8 * (r >> 2) + 4 * lh;
      const float inv = 1.0f / denom[row];
#pragma unroll
      for (int tn = 0; tn < 2; ++tn) {
        const int col = n0 + wn + tn * 32 + l31;
        out[(long)row * MID + col] = acc[tm][tn][r] * inv;
      }
    }
}

extern "C" void kernel_launch(void* const* d_in, const int* in_sizes, int n_in,
                              void* d_out, int out_size, void* d_ws, size_t ws_size,
                              hipStream_t stream) {
  const float* X  = (const float*)d_in[0];
  const float* Wq = (const float*)d_in[1];
  const float* bq = (const float*)d_in[2];
  const float* Wk = (const float*)d_in[3];
  const float* bk = (const float*)d_in[4];
  const float* Wv = (const float*)d_in[5];
  const float* bv = (const float*)d_in[6];

  // workspace layout (bytes). Xb/Wb alias the P region: dead before score writes P.
  //  [0,8M)    Q8 fp8 [8192][1024]   (raw, unnormalized)
  //  [8M,16M)  K8 fp8
  //  [16M,32M) VT bf16 [1024][8192]
  //  [32M,..)  sumsq_q[8192], sumsq_k[8192], denom[8192]  fp32
  //  [33M,161M) P bf16 [8192][8192];  Xb at 33M (16M), Wb at 49M (6M) alias inside
  char* wsb = (char*)d_ws;
  const size_t MB = 1ull << 20;
  unsigned char* Q8  = (unsigned char*)(wsb);
  unsigned char* K8  = (unsigned char*)(wsb + 8 * MB);
  unsigned short* VT = (unsigned short*)(wsb + 16 * MB);
  float* sums        = (float*)(wsb + 32 * MB);
  float* denom       = sums + 2 * SEQ;
  unsigned short* P  = (unsigned short*)(wsb + 33 * MB);
  unsigned short* Xb = (unsigned short*)(wsb + 33 * MB);
  unsigned short* Wb = (unsigned short*)(wsb + 49 * MB);

  hipMemsetAsync(sums, 0, 3 * SEQ * sizeof(float), stream);

  cvt_kernel<<<SEQ * EMB / 1024, 256, 0, stream>>>(X, Xb, SEQ * EMB);
  cvtw_kernel<<<3 * MID * EMB / 1024, 256, 0, stream>>>(Wq, Wk, Wv, Wb);

  qkv_kernel<<<dim3(MID / 128, SEQ / 128, 3), 256, 0, stream>>>(Xb, Wb, bq, bk, bv, Q8, K8, VT, sums);
  score_kernel<<<dim3(SEQ / 128, SEQ / 128), 256, 0, stream>>>(Q8, K8, sums, P, denom);
  out_kernel<<<dim3(SEQ / 128, MID / 128), 256, 0, stream>>>(P, VT, denom, (float*)d_out);
}